// Round 1
// baseline (275.063 us; speedup 1.0000x reference)
//
#include <hip/hip_runtime.h>

// Problem dims (fixed by the reference):
//   B=64, N=576, C=768, CNN=2048, H=12, D=64
// Key insight: softmax over kv_len==1 is exactly 1.0, so:
//   out[b,n,:] = (cnn[b,:] @ Wkv[:, C:2C]) @ Wp + bp   — independent of n,
//   image_patches and Wq are numerically dead.
//
// Pipeline:
//   memset ws (v, y partial accumulators)
//   gemm1: v[64][768]  = cnn[64][2048] @ Wkv[:,768:1536]   (k-split + fp32 HW atomics)
//   gemm2: y[64][768]  = v @ Wp                             (k-split + fp32 HW atomics)
//   bcast: out[b][n][c] = y[b][c] + bp[c]                   (113 MB coalesced float4 stream)

#define B_DIM   64
#define N_DIM   576
#define C_DIM   768
#define CNN_DIM 2048
#define C4_DIM  192          // C/4

// ---------------------------------------------------------------------------
// GEMM1: v += cnn @ Wkv[:, 768:1536]
// Thread task: 1 float4 of columns (c4) x 8 batch rows x one K-chunk of 64.
// grid: 192*8*32 threads = 192 blocks of 256.
// Wkv columns re-read only 8x (b-tiling) instead of 64x.
__global__ __launch_bounds__(256) void gemm1_kernel(
    const float* __restrict__ cnn, const float* __restrict__ Wkv,
    float* __restrict__ v)
{
    int gid = blockIdx.x * 256 + threadIdx.x;
    int c4 = gid % C4_DIM;            // wave-uniform b/s: 192 % 64 == 0
    int bg = (gid / C4_DIM) % 8;
    int s  = gid / (C4_DIM * 8);      // 0..31, K-chunk of 64
    int b0 = bg * 8;
    int k0 = s * 64;

    // Wkv row k, cols [768, 1536): base offset 768 floats (3072 B, 16B-aligned)
    const float4* w4 = (const float4*)(Wkv + C_DIM);   // row stride = 1536/4 = 384

    float4 acc[8];
#pragma unroll
    for (int i = 0; i < 8; ++i) acc[i] = make_float4(0.f, 0.f, 0.f, 0.f);

#pragma unroll 4
    for (int kk = 0; kk < 64; ++kk) {
        int k = k0 + kk;
        float4 w = w4[k * 384 + c4];
#pragma unroll
        for (int i = 0; i < 8; ++i) {
            float a = cnn[(b0 + i) * CNN_DIM + k];   // wave-uniform -> broadcast
            acc[i].x = fmaf(a, w.x, acc[i].x);
            acc[i].y = fmaf(a, w.y, acc[i].y);
            acc[i].z = fmaf(a, w.z, acc[i].z);
            acc[i].w = fmaf(a, w.w, acc[i].w);
        }
    }

#pragma unroll
    for (int i = 0; i < 8; ++i) {
        float* dst = v + (b0 + i) * C_DIM + c4 * 4;
        unsafeAtomicAdd(dst + 0, acc[i].x);
        unsafeAtomicAdd(dst + 1, acc[i].y);
        unsafeAtomicAdd(dst + 2, acc[i].z);
        unsafeAtomicAdd(dst + 3, acc[i].w);
    }
}

// ---------------------------------------------------------------------------
// GEMM2: y += v @ Wp   (bias added in bcast)
// Same structure; K=768 split into 24 chunks of 32. grid: 192*8*24 = 144 blocks.
__global__ __launch_bounds__(256) void gemm2_kernel(
    const float* __restrict__ v, const float* __restrict__ Wp,
    float* __restrict__ y)
{
    int gid = blockIdx.x * 256 + threadIdx.x;
    int c4 = gid % C4_DIM;
    int bg = (gid / C4_DIM) % 8;
    int s  = gid / (C4_DIM * 8);      // 0..23, K-chunk of 32
    int b0 = bg * 8;
    int k0 = s * 32;

    const float4* w4 = (const float4*)Wp;   // row stride = 768/4 = 192

    float4 acc[8];
#pragma unroll
    for (int i = 0; i < 8; ++i) acc[i] = make_float4(0.f, 0.f, 0.f, 0.f);

#pragma unroll 4
    for (int kk = 0; kk < 32; ++kk) {
        int k = k0 + kk;
        float4 w = w4[k * C4_DIM + c4];
#pragma unroll
        for (int i = 0; i < 8; ++i) {
            float a = v[(b0 + i) * C_DIM + k];
            acc[i].x = fmaf(a, w.x, acc[i].x);
            acc[i].y = fmaf(a, w.y, acc[i].y);
            acc[i].z = fmaf(a, w.z, acc[i].z);
            acc[i].w = fmaf(a, w.w, acc[i].w);
        }
    }

#pragma unroll
    for (int i = 0; i < 8; ++i) {
        float* dst = y + (b0 + i) * C_DIM + c4 * 4;
        unsafeAtomicAdd(dst + 0, acc[i].x);
        unsafeAtomicAdd(dst + 1, acc[i].y);
        unsafeAtomicAdd(dst + 2, acc[i].z);
        unsafeAtomicAdd(dst + 3, acc[i].w);
    }
}

// ---------------------------------------------------------------------------
// Broadcast: out[b][n][c4] = y[b][c4] + bp[c4], fully coalesced float4 stream.
// 7,077,888 float4s -> 27648 blocks of 256, exact.
__global__ __launch_bounds__(256) void bcast_kernel(
    const float* __restrict__ y, const float* __restrict__ bp,
    float4* __restrict__ out)
{
    int idx = blockIdx.x * 256 + threadIdx.x;
    int c4 = idx % C4_DIM;
    int b  = idx / (N_DIM * C4_DIM);    // / 110592
    float4 r  = *(const float4*)(y + b * C_DIM + c4 * 4);
    float4 bb = *(const float4*)(bp + c4 * 4);
    r.x += bb.x; r.y += bb.y; r.z += bb.z; r.w += bb.w;
    out[idx] = r;
}

// ---------------------------------------------------------------------------
extern "C" void kernel_launch(void* const* d_in, const int* in_sizes, int n_in,
                              void* d_out, int out_size, void* d_ws, size_t ws_size,
                              hipStream_t stream)
{
    // setup_inputs order: image_patches, cnn_feature_vector, Wq, Wkv, Wp, bp
    const float* cnn = (const float*)d_in[1];
    const float* Wkv = (const float*)d_in[3];
    const float* Wp  = (const float*)d_in[4];
    const float* bp  = (const float*)d_in[5];

    float* v = (float*)d_ws;                  // 64*768 floats = 192 KiB
    float* y = v + B_DIM * C_DIM;             // 64*768 floats = 192 KiB

    // ws is re-poisoned to 0xAA before every call: zero accumulators each time.
    hipMemsetAsync(d_ws, 0, (size_t)2 * B_DIM * C_DIM * sizeof(float), stream);

    gemm1_kernel<<<192, 256, 0, stream>>>(cnn, Wkv, v);
    gemm2_kernel<<<144, 256, 0, stream>>>(v, Wp, y);

    int n_out4 = B_DIM * N_DIM * C4_DIM;      // 7,077,888
    bcast_kernel<<<n_out4 / 256, 256, 0, stream>>>(y, bp, (float4*)d_out);
}

// Round 3
// 232.520 us; speedup vs baseline: 1.1830x; 1.1830x over previous
//
#include <hip/hip_runtime.h>

// Problem dims (fixed): B=64, N=576, C=768, CNN=2048.
// softmax over kv_len==1 == 1.0 exactly, so:
//   out[b,n,:] = (cnn[b,:] @ Wkv[:, C:2C]) @ Wp + bp   — independent of n.
// image_patches / Wq are numerically dead.
//
// R3 = R2 with the nontemporal-store type fixed (native clang vector, not
// HIP_vector_type). 3 dispatches, no atomics, no ws memset:
//   K1 proj_v : v[64][768] = cnn @ Wkv[:,768:1536]; split-K inside the block
//               (32 k-slices x 8 c4-cols = 256 thr), LDS tree-reduce, plain store.
//   K2 proj_y : y[64][768] = v @ Wp + bp; same structure (K=768, 32 slices of 24).
//   K3 bcast  : out[b][n][:] = y[b][:], coalesced 16B nontemporal stream (113 MB).

#define B_DIM   64
#define N_DIM   576
#define C_DIM   768
#define CNN_DIM 2048
#define C4_DIM  192   // C/4

typedef float f4 __attribute__((ext_vector_type(4)));

// ---------------------------------------------------------------------------
// K1: v = cnn @ Wkv[:, 768:1536]
// grid 192 = 8 bgroups x 24 cgroups; block 256 = 32 k-slices x 8 c4-cols.
__global__ __launch_bounds__(256) void proj_v_kernel(
    const float* __restrict__ cnn, const float* __restrict__ Wkv,
    float* __restrict__ v)
{
    __shared__ f4 red[32 * 64];   // 32 KiB

    int tid = threadIdx.x;
    int c4l = tid & 7;
    int s   = tid >> 3;               // 0..31
    int bg  = blockIdx.x & 7;
    int cg  = blockIdx.x >> 3;        // 0..23
    int b0  = bg * 8;
    int c4  = cg * 8 + c4l;
    int k0  = s * 64;

    const f4* w4 = (const f4*)(Wkv + C_DIM);   // row stride 384 f4

    f4 acc[8];
#pragma unroll
    for (int i = 0; i < 8; ++i) acc[i] = (f4)0.f;

#pragma unroll 4
    for (int kk = 0; kk < 64; ++kk) {
        int k = k0 + kk;
        f4 w = w4[k * 384 + c4];
#pragma unroll
        for (int i = 0; i < 8; ++i) {
            float a = cnn[(b0 + i) * CNN_DIM + k];
            acc[i] += a * w;
        }
    }

#pragma unroll
    for (int i = 0; i < 8; ++i) red[s * 64 + i * 8 + c4l] = acc[i];
    __syncthreads();

#pragma unroll
    for (int step = 16; step >= 1; step >>= 1) {
        if (s < step) {
#pragma unroll
            for (int i = 0; i < 8; ++i)
                red[s * 64 + i * 8 + c4l] += red[(s + step) * 64 + i * 8 + c4l];
        }
        __syncthreads();
    }

    if (tid < 64) {
        int i  = tid >> 3;
        int cl = tid & 7;
        *(f4*)(v + (b0 + i) * C_DIM + (cg * 8 + cl) * 4) = red[i * 8 + cl];
    }
}

// ---------------------------------------------------------------------------
// K2: y = v @ Wp + bp. Same structure; K=768 -> 32 slices of 24.
__global__ __launch_bounds__(256) void proj_y_kernel(
    const float* __restrict__ v, const float* __restrict__ Wp,
    const float* __restrict__ bp, float* __restrict__ y)
{
    __shared__ f4 red[32 * 64];

    int tid = threadIdx.x;
    int c4l = tid & 7;
    int s   = tid >> 3;
    int bg  = blockIdx.x & 7;
    int cg  = blockIdx.x >> 3;
    int b0  = bg * 8;
    int c4  = cg * 8 + c4l;
    int k0  = s * 24;

    const f4* w4 = (const f4*)Wp;   // row stride 192 f4

    f4 acc[8];
#pragma unroll
    for (int i = 0; i < 8; ++i) acc[i] = (f4)0.f;

#pragma unroll 4
    for (int kk = 0; kk < 24; ++kk) {
        int k = k0 + kk;
        f4 w = w4[k * C4_DIM + c4];
#pragma unroll
        for (int i = 0; i < 8; ++i) {
            float a = v[(b0 + i) * C_DIM + k];
            acc[i] += a * w;
        }
    }

#pragma unroll
    for (int i = 0; i < 8; ++i) red[s * 64 + i * 8 + c4l] = acc[i];
    __syncthreads();

#pragma unroll
    for (int step = 16; step >= 1; step >>= 1) {
        if (s < step) {
#pragma unroll
            for (int i = 0; i < 8; ++i)
                red[s * 64 + i * 8 + c4l] += red[(s + step) * 64 + i * 8 + c4l];
        }
        __syncthreads();
    }

    if (tid < 64) {
        int i  = tid >> 3;
        int cl = tid & 7;
        f4 r  = red[i * 8 + cl];
        f4 bb = *(const f4*)(bp + (cg * 8 + cl) * 4);
        r += bb;
        *(f4*)(y + (b0 + i) * C_DIM + (cg * 8 + cl) * 4) = r;
    }
}

// ---------------------------------------------------------------------------
// K3: out[b][n][c4] = y[b][c4]; 7,077,888 x 16B nontemporal stream.
__global__ __launch_bounds__(256) void bcast_kernel(
    const f4* __restrict__ y4, f4* __restrict__ out)
{
    int idx = blockIdx.x * 256 + threadIdx.x;
    int c4  = idx % C4_DIM;
    int b   = idx / (N_DIM * C4_DIM);
    f4 r = y4[b * C4_DIM + c4];
    __builtin_nontemporal_store(r, &out[idx]);
}

// ---------------------------------------------------------------------------
extern "C" void kernel_launch(void* const* d_in, const int* in_sizes, int n_in,
                              void* d_out, int out_size, void* d_ws, size_t ws_size,
                              hipStream_t stream)
{
    // inputs: image_patches, cnn_feature_vector, Wq, Wkv, Wp, bp
    const float* cnn = (const float*)d_in[1];
    const float* Wkv = (const float*)d_in[3];
    const float* Wp  = (const float*)d_in[4];
    const float* bp  = (const float*)d_in[5];

    float* v = (float*)d_ws;              // 192 KiB
    float* y = v + B_DIM * C_DIM;         // 192 KiB

    proj_v_kernel<<<192, 256, 0, stream>>>(cnn, Wkv, v);
    proj_y_kernel<<<192, 256, 0, stream>>>(v, Wp, bp, y);

    int n_out4 = B_DIM * N_DIM * C4_DIM;  // 7,077,888
    bcast_kernel<<<n_out4 / 256, 256, 0, stream>>>((const f4*)y, (f4*)d_out);
}

// Round 4
// 229.948 us; speedup vs baseline: 1.1962x; 1.0112x over previous
//
#include <hip/hip_runtime.h>

// Problem dims (fixed): B=64, N=576, C=768, CNN=2048.
// softmax over kv_len==1 == 1.0 exactly, so:
//   out[b,n,:] = (cnn[b,:] @ Wkv[:, C:2C]) @ Wp + bp   — independent of n.
// image_patches / Wq are numerically dead.
//
// R4: 2 dispatches (fuse GEMM2 + broadcast):
//   K1 proj_v : v[64][768] = cnn @ Wkv[:,768:1536]; split-K inside the block
//               (32 k-slices x 8 c4-cols = 256 thr), LDS tree-reduce, plain store.
//   K2 fused  : per (b, ctile-of-64-floats) block: y-slice = v[b]·Wp[:,ctile]+bp
//               (16 kslice x 16 col threads, LDS reduce), then stream the
//               576-row output slice with nontemporal 16B stores (147 KB/block).

#define B_DIM   64
#define N_DIM   576
#define C_DIM   768
#define CNN_DIM 2048
#define C4_DIM  192   // C/4

typedef float f4 __attribute__((ext_vector_type(4)));

// ---------------------------------------------------------------------------
// K1: v = cnn @ Wkv[:, 768:1536]
// grid 192 = 8 bgroups x 24 cgroups; block 256 = 32 k-slices x 8 c4-cols.
__global__ __launch_bounds__(256) void proj_v_kernel(
    const float* __restrict__ cnn, const float* __restrict__ Wkv,
    float* __restrict__ v)
{
    __shared__ f4 red[32 * 64];   // 32 KiB

    int tid = threadIdx.x;
    int c4l = tid & 7;
    int s   = tid >> 3;               // 0..31
    int bg  = blockIdx.x & 7;
    int cg  = blockIdx.x >> 3;        // 0..23
    int b0  = bg * 8;
    int c4  = cg * 8 + c4l;
    int k0  = s * 64;

    const f4* w4 = (const f4*)(Wkv + C_DIM);   // row stride 384 f4

    f4 acc[8];
#pragma unroll
    for (int i = 0; i < 8; ++i) acc[i] = (f4)0.f;

#pragma unroll 4
    for (int kk = 0; kk < 64; ++kk) {
        int k = k0 + kk;
        f4 w = w4[k * 384 + c4];
#pragma unroll
        for (int i = 0; i < 8; ++i) {
            float a = cnn[(b0 + i) * CNN_DIM + k];
            acc[i] += a * w;
        }
    }

#pragma unroll
    for (int i = 0; i < 8; ++i) red[s * 64 + i * 8 + c4l] = acc[i];
    __syncthreads();

#pragma unroll
    for (int step = 16; step >= 1; step >>= 1) {
        if (s < step) {
#pragma unroll
            for (int i = 0; i < 8; ++i)
                red[s * 64 + i * 8 + c4l] += red[(s + step) * 64 + i * 8 + c4l];
        }
        __syncthreads();
    }

    if (tid < 64) {
        int i  = tid >> 3;
        int cl = tid & 7;
        *(f4*)(v + (b0 + i) * C_DIM + (cg * 8 + cl) * 4) = red[i * 8 + cl];
    }
}

// ---------------------------------------------------------------------------
// K2: fused y-slice compute + broadcast.
// grid: (12 ctiles, 64 b). block 256 = 16 kslices x 16 f4-cols.
// Phase 1: ytile[16 f4] = v[b][:] @ Wp[:, ctile] + bp[ctile]  (LDS tree-reduce)
// Phase 2: 36 iterations of coalesced nontemporal stores (9216 f4 per block).
__global__ __launch_bounds__(256) void proj_bcast_kernel(
    const float* __restrict__ v, const float* __restrict__ Wp,
    const float* __restrict__ bp, f4* __restrict__ out)
{
    __shared__ f4 red[16 * 16];   // 4 KiB

    int tid = threadIdx.x;
    int col = tid & 15;           // f4 column within ctile
    int ks  = tid >> 4;           // 0..15 k-slice
    int ct  = blockIdx.x;         // 0..11
    int b   = blockIdx.y;         // 0..63

    const f4* wp4 = (const f4*)Wp;            // row stride 192 f4
    const float* vb = v + b * C_DIM;

    // Phase 1: each thread reduces 48 k's for its f4 column.
    f4 acc = (f4)0.f;
    int wcol = ct * 16 + col;
#pragma unroll 4
    for (int kk = 0; kk < 48; ++kk) {
        int k = ks * 48 + kk;
        acc += vb[k] * wp4[k * C4_DIM + wcol];
    }
    red[ks * 16 + col] = acc;
    __syncthreads();

#pragma unroll
    for (int step = 8; step >= 1; step >>= 1) {
        if (ks < step)
            red[ks * 16 + col] += red[(ks + step) * 16 + col];
        __syncthreads();
    }
    if (tid < 16)
        red[tid] += ((const f4*)bp)[ct * 16 + tid];
    __syncthreads();

    // Phase 2: broadcast over n. col is iteration-invariant (256 % 16 == 0).
    f4 yv = red[col];
    f4* base = out + (size_t)b * (N_DIM * C4_DIM) + ct * 16 + col;
    int nrow = tid >> 4;          // starting n, advances by 16 per iter
#pragma unroll 4
    for (int iter = 0; iter < 36; ++iter) {
        __builtin_nontemporal_store(yv, base + (nrow + iter * 16) * C4_DIM);
    }
}

// ---------------------------------------------------------------------------
extern "C" void kernel_launch(void* const* d_in, const int* in_sizes, int n_in,
                              void* d_out, int out_size, void* d_ws, size_t ws_size,
                              hipStream_t stream)
{
    // inputs: image_patches, cnn_feature_vector, Wq, Wkv, Wp, bp
    const float* cnn = (const float*)d_in[1];
    const float* Wkv = (const float*)d_in[3];
    const float* Wp  = (const float*)d_in[4];
    const float* bp  = (const float*)d_in[5];

    float* v = (float*)d_ws;              // 192 KiB

    proj_v_kernel<<<192, 256, 0, stream>>>(cnn, Wkv, v);
    proj_bcast_kernel<<<dim3(12, 64), 256, 0, stream>>>(v, Wp, bp, (f4*)d_out);
}